// Round 12
// baseline (152.038 us; speedup 1.0000x reference)
//
#include <hip/hip_runtime.h>
#include <hip/hip_bf16.h>
#include <math.h>

#define N_ROWS 8192
#define D_DIM  256
#define BM 128
#define BN 64
#define JSPLIT 16
#define JRANGE (N_ROWS / JSPLIT)     // 512
#define NT (JRANGE / BN)             // 8 j-steps per block

typedef __attribute__((ext_vector_type(4))) float f32x4;

// total scale: exp(dot*2) == exp2(dot * 2*log2(e)); sqrt folded onto A and B
#define CAST_SCALE 1.6986388f        // sqrt(2 * log2(e))

__device__ __forceinline__ float fast_exp2(float x) {
#if __has_builtin(__builtin_amdgcn_exp2f)
    return __builtin_amdgcn_exp2f(x);
#else
    return exp2f(x);
#endif
}

// ------- kernel 1: L2-normalize rows, scale, cast to fp8 e4m3 (+ zero accum) -
__global__ void norm_cast_kernel(const float* __restrict__ out0,
                                 const float* __restrict__ out1,
                                 unsigned char* __restrict__ a_f8,
                                 unsigned char* __restrict__ b_f8,
                                 float* __restrict__ zero_me) {   // pos+all, 2*N floats
    int gtid = blockIdx.x * blockDim.x + threadIdx.x;
    if (gtid < 2 * N_ROWS) zero_me[gtid] = 0.0f;

    int wave = gtid >> 6;
    int lane = threadIdx.x & 63;
    const float* src    = (wave < N_ROWS) ? out0 : out1;
    unsigned char* dst  = (wave < N_ROWS) ? a_f8 : b_f8;
    int row = (wave < N_ROWS) ? wave : wave - N_ROWS;

    float4 v = *reinterpret_cast<const float4*>(src + (size_t)row * D_DIM + lane * 4);
    float ss = v.x * v.x + v.y * v.y + v.z * v.z + v.w * v.w;
    #pragma unroll
    for (int off = 32; off; off >>= 1) ss += __shfl_xor(ss, off);
    float inv = CAST_SCALE / fmaxf(sqrtf(ss), 1e-12f);

    int packed = __builtin_amdgcn_cvt_pk_fp8_f32(v.x * inv, v.y * inv, 0, 0);
    packed     = __builtin_amdgcn_cvt_pk_fp8_f32(v.z * inv, v.w * inv, packed, 1);
    *reinterpret_cast<unsigned int*>(dst + (size_t)row * D_DIM + lane * 4) =
        (unsigned int)packed;
}

// ------- kernel 2: fp8 flash-style fused GEMM + exp2 + masked row-sums ------
// 1024 blocks = 64 row-tiles x 16 j-splits (jsplit = blockIdx&15; jsplit%8 =
// XCD, so each XCD's two 128KB B-slices stay L2-resident). 4 blocks/CU =
// 4 waves/SIMD for stall hiding. 4 waves in 2x2, wave-tile 64x32. A-slice
// PINNED in regs (64 VGPR fp8). B double-buffered in LDS (2x16 KB), staged
// via global_load_lds(16B), 16B-slot XOR swizzle; b128 reads conflict-free
// under the K-permutation pairing (low 8B -> ks=2j, high 8B -> ks=2j+1).
__global__ __launch_bounds__(256, 4)
void fused_flash_kernel(const unsigned char* __restrict__ A,
                        const unsigned char* __restrict__ B,
                        const int* __restrict__ labels,
                        float* __restrict__ pos_sum,
                        float* __restrict__ all_sum) {
    __shared__ unsigned char Bs[2][BN * D_DIM];   // 2 x 16 KB

    const int tid    = threadIdx.x;
    const int lane   = tid & 63;
    const int wid    = tid >> 6;        // 0..3
    const int wr     = wid >> 1;        // 0..1  (64-row band)
    const int wc     = wid & 1;         // 0..1  (32-col half)
    const int lane16 = lane & 15;
    const int kgrp   = lane >> 4;       // 0..3

    const int jsplit = blockIdx.x & 15;
    const int rowt   = blockIdx.x >> 4;
    const int i0     = rowt * BM;
    const int jbase  = jsplit * JRANGE;

    // ---- A fragments -> registers (once), PINNED (64 VGPR fp8) ----
    // b128 at row bytes [j*64 + kgrp*16, +16): low 8B -> ks=2j, high -> ks=2j+1
    long af[4][8];
    #pragma unroll
    for (int m = 0; m < 4; ++m) {
        const unsigned char* ap =
            A + (size_t)(i0 + wr * 64 + m * 16 + lane16) * D_DIM + kgrp * 16;
        #pragma unroll
        for (int j = 0; j < 4; ++j) {
            long2 v = *reinterpret_cast<const long2*>(ap + j * 64);
            af[m][2 * j]     = v.x;
            af[m][2 * j + 1] = v.y;
        }
    }
    #pragma unroll
    for (int m = 0; m < 4; ++m)
        #pragma unroll
        for (int ks = 0; ks < 8; ++ks)
            asm volatile("" : "+v"(af[m][ks]));

    // row labels (0..99 fit in a byte), packed 4-per-int, pinned
    int labp[4];
    #pragma unroll
    for (int m = 0; m < 4; ++m) {
        int4 v = *reinterpret_cast<const int4*>(labels + i0 + wr * 64 + m * 16 + kgrp * 4);
        labp[m] = v.x | (v.y << 8) | (v.z << 16) | (v.w << 24);
        asm volatile("" : "+v"(labp[m]));
    }

    // ---- B staging: 16 chunks of 1KB (4 rows x 256B), 4 per wave ----
    // LDS[row][phys] = global[row][phys ^ (row&15)]  (16B slots, 16 per row)
    auto stage = [&](int buf, int t) {
        const int jrow0 = jbase + t * BN;
        #pragma unroll
        for (int cc = 0; cc < 4; ++cc) {
            int c  = wid * 4 + cc;                  // chunk 0..15 (wave-uniform)
            int gr = jrow0 + c * 4 + kgrp;          // global B row
            const unsigned char* src =
                B + (size_t)gr * D_DIM + ((lane16 ^ (gr & 15)) << 4);
            __builtin_amdgcn_global_load_lds(
                (const __attribute__((address_space(1))) void*)src,
                (__attribute__((address_space(3))) void*)(&Bs[buf][0] + c * 1024),
                16, 0, 0);
        }
    };

    float allp[4][4] = {};
    float posp[4][4] = {};

    stage(0, 0);
    __syncthreads();

    for (int t = 0; t < NT; ++t) {
        const int cur = t & 1;
        if (t + 1 < NT) stage(cur ^ 1, t + 1);

        // column labels early (hide under MFMA)
        const int jc    = jbase + t * BN + wc * 32 + lane16;
        const int labc0 = labels[jc];
        const int labc1 = labels[jc + 16];

        // ---- hoist all 8 b128 B-loads, then 64 MFMAs ----
        long bl[2][4], bh[2][4];
        #pragma unroll
        for (int n = 0; n < 2; ++n) {
            const int tr = wc * 32 + n * 16 + lane16;     // B row (output col)
            #pragma unroll
            for (int j = 0; j < 4; ++j) {
                int phys = (j * 4 + kgrp) ^ lane16;       // swizzled 16B slot
                long2 v = *reinterpret_cast<const long2*>(
                    &Bs[cur][0] + tr * 256 + (phys << 4));
                bl[n][j] = v.x;                           // ks = 2j
                bh[n][j] = v.y;                           // ks = 2j+1
            }
        }

        f32x4 acc[4][2] = {};
        __builtin_amdgcn_s_setprio(1);
        #pragma unroll
        for (int j = 0; j < 4; ++j) {
            #pragma unroll
            for (int m = 0; m < 4; ++m)
                #pragma unroll
                for (int n = 0; n < 2; ++n)
                    acc[m][n] = __builtin_amdgcn_mfma_f32_16x16x32_fp8_fp8(
                        af[m][2 * j], bl[n][j], acc[m][n], 0, 0, 0);
            #pragma unroll
            for (int m = 0; m < 4; ++m)
                #pragma unroll
                for (int n = 0; n < 2; ++n)
                    acc[m][n] = __builtin_amdgcn_mfma_f32_16x16x32_fp8_fp8(
                        af[m][2 * j + 1], bh[n][j], acc[m][n], 0, 0, 0);
        }
        __builtin_amdgcn_s_setprio(0);

        __syncthreads();   // all reads of Bs[cur] done; stage(t+1) drained

        // ---- epilogue: exp2 + mask, accumulate row sums in registers ----
        #pragma unroll
        for (int m = 0; m < 4; ++m) {
            #pragma unroll
            for (int r = 0; r < 4; ++r) {
                float e0 = fast_exp2(acc[m][0][r]);   // == exp(logit/T)
                float e1 = fast_exp2(acc[m][1][r]);
                allp[m][r] += e0 + e1;
                int lr = (labp[m] >> (r * 8)) & 0xFF;
                posp[m][r] += (lr == labc0 ? e0 : 0.0f) + (lr == labc1 ? e1 : 0.0f);
            }
        }
    }

    // ---- final: reduce across the 16 col-lanes, one atomic per row ----
    #pragma unroll
    for (int m = 0; m < 4; ++m) {
        #pragma unroll
        for (int r = 0; r < 4; ++r) {
            float a = allp[m][r], p = posp[m][r];
            #pragma unroll
            for (int off = 1; off < 16; off <<= 1) {
                a += __shfl_xor(a, off);
                p += __shfl_xor(p, off);
            }
            if (lane16 == 0) {
                int grow = i0 + wr * 64 + m * 16 + kgrp * 4 + r;
                atomicAdd(&all_sum[grow], a);
                atomicAdd(&pos_sum[grow], p);
            }
        }
    }
}

// ---------------- kernel 3: final loss reduction ----------------------------
__global__ void loss_kernel(const float* __restrict__ pos_sum,
                            const float* __restrict__ all_sum,
                            float* __restrict__ out) {
    float acc = 0.0f;
    for (int i = threadIdx.x; i < N_ROWS; i += 1024)
        acc += logf(pos_sum[i] / all_sum[i]);
    #pragma unroll
    for (int off = 32; off; off >>= 1) acc += __shfl_xor(acc, off);
    __shared__ float red[16];
    int wv = threadIdx.x >> 6, lane = threadIdx.x & 63;
    if (lane == 0) red[wv] = acc;
    __syncthreads();
    if (threadIdx.x < 64) {
        float s = (threadIdx.x < 16) ? red[threadIdx.x] : 0.0f;
        #pragma unroll
        for (int off = 8; off; off >>= 1) s += __shfl_xor(s, off);
        if (threadIdx.x == 0) out[0] = -s / (float)N_ROWS;
    }
}

// ---------------- launch -----------------------------------------------------
extern "C" void kernel_launch(void* const* d_in, const int* in_sizes, int n_in,
                              void* d_out, int out_size, void* d_ws, size_t ws_size,
                              hipStream_t stream) {
    const float* out0   = (const float*)d_in[0];
    const float* out1   = (const float*)d_in[1];
    const int*   labels = (const int*)d_in[2];
    float*       out    = (float*)d_out;

    unsigned char* a_f8 = (unsigned char*)d_ws;
    unsigned char* b_f8 = a_f8 + (size_t)N_ROWS * D_DIM;
    float* pos  = (float*)(b_f8 + (size_t)N_ROWS * D_DIM);
    float* alls = pos + N_ROWS;

    norm_cast_kernel<<<2 * N_ROWS / 4, 256, 0, stream>>>(out0, out1, a_f8, b_f8, pos);

    fused_flash_kernel<<<JSPLIT * (N_ROWS / BM), 256, 0, stream>>>(a_f8, b_f8, labels, pos, alls);

    loss_kernel<<<1, 1024, 0, stream>>>(pos, alls, out);
}

// Round 13
// 65.595 us; speedup vs baseline: 2.3178x; 2.3178x over previous
//
#include <hip/hip_runtime.h>
#include <hip/hip_bf16.h>
#include <math.h>

#define N_ROWS 8192
#define D_DIM  256
#define BM 128
#define BN 64
#define JSPLIT 16
#define JRANGE (N_ROWS / JSPLIT)     // 512
#define NT (JRANGE / BN)             // 8 j-steps per block

typedef __attribute__((ext_vector_type(4))) float f32x4;

// total scale: exp(dot*2) == exp2(dot * 2*log2(e)); sqrt folded onto A and B
#define CAST_SCALE 1.6986388f        // sqrt(2 * log2(e))

__device__ __forceinline__ float fast_exp2(float x) {
#if __has_builtin(__builtin_amdgcn_exp2f)
    return __builtin_amdgcn_exp2f(x);
#else
    return exp2f(x);
#endif
}

// ------- kernel 1: L2-normalize rows, scale, cast to fp8 e4m3 (+ zero accum) -
__global__ void norm_cast_kernel(const float* __restrict__ out0,
                                 const float* __restrict__ out1,
                                 unsigned char* __restrict__ a_f8,
                                 unsigned char* __restrict__ b_f8,
                                 float* __restrict__ zero_me) {   // pos+all, 2*N floats
    int gtid = blockIdx.x * blockDim.x + threadIdx.x;
    if (gtid < 2 * N_ROWS) zero_me[gtid] = 0.0f;

    int wave = gtid >> 6;
    int lane = threadIdx.x & 63;
    const float* src    = (wave < N_ROWS) ? out0 : out1;
    unsigned char* dst  = (wave < N_ROWS) ? a_f8 : b_f8;
    int row = (wave < N_ROWS) ? wave : wave - N_ROWS;

    float4 v = *reinterpret_cast<const float4*>(src + (size_t)row * D_DIM + lane * 4);
    float ss = v.x * v.x + v.y * v.y + v.z * v.z + v.w * v.w;
    #pragma unroll
    for (int off = 32; off; off >>= 1) ss += __shfl_xor(ss, off);
    float inv = CAST_SCALE / fmaxf(sqrtf(ss), 1e-12f);

    int packed = __builtin_amdgcn_cvt_pk_fp8_f32(v.x * inv, v.y * inv, 0, 0);
    packed     = __builtin_amdgcn_cvt_pk_fp8_f32(v.z * inv, v.w * inv, packed, 1);
    *reinterpret_cast<unsigned int*>(dst + (size_t)row * D_DIM + lane * 4) =
        (unsigned int)packed;
}

// ------- kernel 2: fp8 flash-style fused GEMM + exp2 + masked row-sums ------
// 1024 blocks = 64 row-tiles x 16 j-splits (jsplit = blockIdx&15; jsplit&7 =
// XCD -> both 128KB B-slices of an XCD stay L2-resident). Actual VGPR ~104
// => 4 blocks/CU co-resident (4 waves/SIMD) — the r11 grid was the occupancy
// limiter, NOT the register file. NOTE: launch_bounds stays (256,2); the
// (256,4) cap in r12 crushed the allocator to 64 VGPR and spilled everything.
// 4 waves in 2x2, wave-tile 64x32, A-slice PINNED in regs (64 VGPR fp8).
// B double-buffered in LDS (2x16 KB), global_load_lds(16B) staging, 16B-slot
// XOR swizzle; b128 reads conflict-free under the K-permutation pairing.
__global__ __launch_bounds__(256, 2)
void fused_flash_kernel(const unsigned char* __restrict__ A,
                        const unsigned char* __restrict__ B,
                        const int* __restrict__ labels,
                        float* __restrict__ pos_sum,
                        float* __restrict__ all_sum) {
    __shared__ unsigned char Bs[2][BN * D_DIM];   // 2 x 16 KB

    const int tid    = threadIdx.x;
    const int lane   = tid & 63;
    const int wid    = tid >> 6;        // 0..3
    const int wr     = wid >> 1;        // 0..1  (64-row band)
    const int wc     = wid & 1;         // 0..1  (32-col half)
    const int lane16 = lane & 15;
    const int kgrp   = lane >> 4;       // 0..3

    const int jsplit = blockIdx.x & 15;
    const int rowt   = blockIdx.x >> 4;
    const int i0     = rowt * BM;
    const int jbase  = jsplit * JRANGE;

    // ---- A fragments -> registers (once), PINNED (64 VGPR fp8) ----
    // b128 at row bytes [j*64 + kgrp*16, +16): low 8B -> ks=2j, high -> ks=2j+1
    long af[4][8];
    #pragma unroll
    for (int m = 0; m < 4; ++m) {
        const unsigned char* ap =
            A + (size_t)(i0 + wr * 64 + m * 16 + lane16) * D_DIM + kgrp * 16;
        #pragma unroll
        for (int j = 0; j < 4; ++j) {
            long2 v = *reinterpret_cast<const long2*>(ap + j * 64);
            af[m][2 * j]     = v.x;
            af[m][2 * j + 1] = v.y;
        }
    }
    #pragma unroll
    for (int m = 0; m < 4; ++m)
        #pragma unroll
        for (int ks = 0; ks < 8; ++ks)
            asm volatile("" : "+v"(af[m][ks]));

    // row labels (0..99 fit in a byte), packed 4-per-int, pinned
    int labp[4];
    #pragma unroll
    for (int m = 0; m < 4; ++m) {
        int4 v = *reinterpret_cast<const int4*>(labels + i0 + wr * 64 + m * 16 + kgrp * 4);
        labp[m] = v.x | (v.y << 8) | (v.z << 16) | (v.w << 24);
        asm volatile("" : "+v"(labp[m]));
    }

    // ---- B staging: 16 chunks of 1KB (4 rows x 256B), 4 per wave ----
    // LDS[row][phys] = global[row][phys ^ (row&15)]  (16B slots, 16 per row)
    auto stage = [&](int buf, int t) {
        const int jrow0 = jbase + t * BN;
        #pragma unroll
        for (int cc = 0; cc < 4; ++cc) {
            int c  = wid * 4 + cc;                  // chunk 0..15 (wave-uniform)
            int gr = jrow0 + c * 4 + kgrp;          // global B row
            const unsigned char* src =
                B + (size_t)gr * D_DIM + ((lane16 ^ (gr & 15)) << 4);
            __builtin_amdgcn_global_load_lds(
                (const __attribute__((address_space(1))) void*)src,
                (__attribute__((address_space(3))) void*)(&Bs[buf][0] + c * 1024),
                16, 0, 0);
        }
    };

    float allp[4][4] = {};
    float posp[4][4] = {};

    stage(0, 0);
    __syncthreads();

    for (int t = 0; t < NT; ++t) {
        const int cur = t & 1;
        if (t + 1 < NT) stage(cur ^ 1, t + 1);

        // column labels early (hide under MFMA)
        const int jc    = jbase + t * BN + wc * 32 + lane16;
        const int labc0 = labels[jc];
        const int labc1 = labels[jc + 16];

        // ---- hoist all 8 b128 B-loads, then 64 MFMAs ----
        long bl[2][4], bh[2][4];
        #pragma unroll
        for (int n = 0; n < 2; ++n) {
            const int tr = wc * 32 + n * 16 + lane16;     // B row (output col)
            #pragma unroll
            for (int j = 0; j < 4; ++j) {
                int phys = (j * 4 + kgrp) ^ lane16;       // swizzled 16B slot
                long2 v = *reinterpret_cast<const long2*>(
                    &Bs[cur][0] + tr * 256 + (phys << 4));
                bl[n][j] = v.x;                           // ks = 2j
                bh[n][j] = v.y;                           // ks = 2j+1
            }
        }

        f32x4 acc[4][2] = {};
        __builtin_amdgcn_s_setprio(1);
        #pragma unroll
        for (int j = 0; j < 4; ++j) {
            #pragma unroll
            for (int m = 0; m < 4; ++m)
                #pragma unroll
                for (int n = 0; n < 2; ++n)
                    acc[m][n] = __builtin_amdgcn_mfma_f32_16x16x32_fp8_fp8(
                        af[m][2 * j], bl[n][j], acc[m][n], 0, 0, 0);
            #pragma unroll
            for (int m = 0; m < 4; ++m)
                #pragma unroll
                for (int n = 0; n < 2; ++n)
                    acc[m][n] = __builtin_amdgcn_mfma_f32_16x16x32_fp8_fp8(
                        af[m][2 * j + 1], bh[n][j], acc[m][n], 0, 0, 0);
        }
        __builtin_amdgcn_s_setprio(0);

        __syncthreads();   // all reads of Bs[cur] done; stage(t+1) drained

        // ---- epilogue: exp2 + mask, accumulate row sums in registers ----
        #pragma unroll
        for (int m = 0; m < 4; ++m) {
            #pragma unroll
            for (int r = 0; r < 4; ++r) {
                float e0 = fast_exp2(acc[m][0][r]);   // == exp(logit/T)
                float e1 = fast_exp2(acc[m][1][r]);
                allp[m][r] += e0 + e1;
                int lr = (labp[m] >> (r * 8)) & 0xFF;
                posp[m][r] += (lr == labc0 ? e0 : 0.0f) + (lr == labc1 ? e1 : 0.0f);
            }
        }
    }

    // ---- final: reduce across the 16 col-lanes, one atomic per row ----
    #pragma unroll
    for (int m = 0; m < 4; ++m) {
        #pragma unroll
        for (int r = 0; r < 4; ++r) {
            float a = allp[m][r], p = posp[m][r];
            #pragma unroll
            for (int off = 1; off < 16; off <<= 1) {
                a += __shfl_xor(a, off);
                p += __shfl_xor(p, off);
            }
            if (lane16 == 0) {
                int grow = i0 + wr * 64 + m * 16 + kgrp * 4 + r;
                atomicAdd(&all_sum[grow], a);
                atomicAdd(&pos_sum[grow], p);
            }
        }
    }
}

// ---------------- kernel 3: final loss reduction ----------------------------
__global__ void loss_kernel(const float* __restrict__ pos_sum,
                            const float* __restrict__ all_sum,
                            float* __restrict__ out) {
    float acc = 0.0f;
    for (int i = threadIdx.x; i < N_ROWS; i += 1024)
        acc += logf(pos_sum[i] / all_sum[i]);
    #pragma unroll
    for (int off = 32; off; off >>= 1) acc += __shfl_xor(acc, off);
    __shared__ float red[16];
    int wv = threadIdx.x >> 6, lane = threadIdx.x & 63;
    if (lane == 0) red[wv] = acc;
    __syncthreads();
    if (threadIdx.x < 64) {
        float s = (threadIdx.x < 16) ? red[threadIdx.x] : 0.0f;
        #pragma unroll
        for (int off = 8; off; off >>= 1) s += __shfl_xor(s, off);
        if (threadIdx.x == 0) out[0] = -s / (float)N_ROWS;
    }
}

// ---------------- launch -----------------------------------------------------
extern "C" void kernel_launch(void* const* d_in, const int* in_sizes, int n_in,
                              void* d_out, int out_size, void* d_ws, size_t ws_size,
                              hipStream_t stream) {
    const float* out0   = (const float*)d_in[0];
    const float* out1   = (const float*)d_in[1];
    const int*   labels = (const int*)d_in[2];
    float*       out    = (float*)d_out;

    unsigned char* a_f8 = (unsigned char*)d_ws;
    unsigned char* b_f8 = a_f8 + (size_t)N_ROWS * D_DIM;
    float* pos  = (float*)(b_f8 + (size_t)N_ROWS * D_DIM);
    float* alls = pos + N_ROWS;

    norm_cast_kernel<<<2 * N_ROWS / 4, 256, 0, stream>>>(out0, out1, a_f8, b_f8, pos);

    fused_flash_kernel<<<JSPLIT * (N_ROWS / BM), 256, 0, stream>>>(a_f8, b_f8, labels, pos, alls);

    loss_kernel<<<1, 1024, 0, stream>>>(pos, alls, out);
}

// Round 14
// 52.527 us; speedup vs baseline: 2.8945x; 1.2488x over previous
//
#include <hip/hip_runtime.h>
#include <hip/hip_bf16.h>
#include <math.h>

#define N_ROWS 8192
#define D_DIM  256
#define BM 128
#define BN 64
#define JSPLIT 8
#define JRANGE (N_ROWS / JSPLIT)     // 1024
#define NT (JRANGE / BN)             // 16 j-steps per block

typedef __attribute__((ext_vector_type(4))) float f32x4;

// total scale: exp(dot*2) == exp2(dot * 2*log2(e)); sqrt folded onto A and B
#define CAST_SCALE 1.6986388f        // sqrt(2 * log2(e))

__device__ __forceinline__ float fast_exp2(float x) {
#if __has_builtin(__builtin_amdgcn_exp2f)
    return __builtin_amdgcn_exp2f(x);
#else
    return exp2f(x);
#endif
}

// ------- kernel 1: L2-normalize rows, scale, cast to fp8 e4m3 (+ zero accum) -
__global__ void norm_cast_kernel(const float* __restrict__ out0,
                                 const float* __restrict__ out1,
                                 unsigned char* __restrict__ a_f8,
                                 unsigned char* __restrict__ b_f8,
                                 float* __restrict__ zero_me) {   // pos+all, 2*N floats
    int gtid = blockIdx.x * blockDim.x + threadIdx.x;
    if (gtid < 2 * N_ROWS) zero_me[gtid] = 0.0f;

    int wave = gtid >> 6;
    int lane = threadIdx.x & 63;
    const float* src    = (wave < N_ROWS) ? out0 : out1;
    unsigned char* dst  = (wave < N_ROWS) ? a_f8 : b_f8;
    int row = (wave < N_ROWS) ? wave : wave - N_ROWS;

    float4 v = *reinterpret_cast<const float4*>(src + (size_t)row * D_DIM + lane * 4);
    float ss = v.x * v.x + v.y * v.y + v.z * v.z + v.w * v.w;
    #pragma unroll
    for (int off = 32; off; off >>= 1) ss += __shfl_xor(ss, off);
    float inv = CAST_SCALE / fmaxf(sqrtf(ss), 1e-12f);

    int packed = __builtin_amdgcn_cvt_pk_fp8_f32(v.x * inv, v.y * inv, 0, 0);
    packed     = __builtin_amdgcn_cvt_pk_fp8_f32(v.z * inv, v.w * inv, packed, 1);
    *reinterpret_cast<unsigned int*>(dst + (size_t)row * D_DIM + lane * 4) =
        (unsigned int)packed;
}

// ------- kernel 2: fp8 flash-style fused GEMM + exp2 + masked row-sums ------
// r11 structure (43.6us champion) + T3/T4: triple-buffered LDS, stage 2 tiles
// ahead, counted vmcnt(4) + raw s_barrier (never vmcnt(0) in the main loop) so
// staging latency spans the whole j-step instead of being drained per-step.
// 512 blocks = 64 row-tiles x 8 j-splits; 4 waves 2x2; wave-tile 64x32;
// A-slice PINNED in regs (64 VGPR fp8); b128 LDS reads conflict-free under the
// K-permutation pairing + 16B-slot XOR swizzle.
__global__ __launch_bounds__(256, 2)
void fused_flash_kernel(const unsigned char* __restrict__ A,
                        const unsigned char* __restrict__ B,
                        const int* __restrict__ labels,
                        float* __restrict__ pos_sum,
                        float* __restrict__ all_sum) {
    __shared__ unsigned char Bs[3][BN * D_DIM];   // 3 x 16 KB

    const int tid    = threadIdx.x;
    const int lane   = tid & 63;
    const int wid    = tid >> 6;        // 0..3
    const int wr     = wid >> 1;        // 0..1  (64-row band)
    const int wc     = wid & 1;         // 0..1  (32-col half)
    const int lane16 = lane & 15;
    const int kgrp   = lane >> 4;       // 0..3

    const int jsplit = blockIdx.x & 7;
    const int rowt   = blockIdx.x >> 3;
    const int i0     = rowt * BM;
    const int jbase  = jsplit * JRANGE;

    // ---- A fragments -> registers (once), PINNED (64 VGPR fp8) ----
    // b128 at row bytes [j*64 + kgrp*16, +16): low 8B -> ks=2j, high -> ks=2j+1
    long af[4][8];
    #pragma unroll
    for (int m = 0; m < 4; ++m) {
        const unsigned char* ap =
            A + (size_t)(i0 + wr * 64 + m * 16 + lane16) * D_DIM + kgrp * 16;
        #pragma unroll
        for (int j = 0; j < 4; ++j) {
            long2 v = *reinterpret_cast<const long2*>(ap + j * 64);
            af[m][2 * j]     = v.x;
            af[m][2 * j + 1] = v.y;
        }
    }
    #pragma unroll
    for (int m = 0; m < 4; ++m)
        #pragma unroll
        for (int ks = 0; ks < 8; ++ks)
            asm volatile("" : "+v"(af[m][ks]));

    // row labels (0..99 fit in a byte), packed 4-per-int, pinned
    int labp[4];
    #pragma unroll
    for (int m = 0; m < 4; ++m) {
        int4 v = *reinterpret_cast<const int4*>(labels + i0 + wr * 64 + m * 16 + kgrp * 4);
        labp[m] = v.x | (v.y << 8) | (v.z << 16) | (v.w << 24);
        asm volatile("" : "+v"(labp[m]));
    }

    // ---- B staging: 16 chunks of 1KB (4 rows x 256B), 4 per wave ----
    // LDS[row][phys] = global[row][phys ^ (row&15)]  (16B slots, 16 per row)
    auto stage = [&](int buf, int t) {
        const int jrow0 = jbase + t * BN;
        #pragma unroll
        for (int cc = 0; cc < 4; ++cc) {
            int c  = wid * 4 + cc;                  // chunk 0..15 (wave-uniform)
            int gr = jrow0 + c * 4 + kgrp;          // global B row
            const unsigned char* src =
                B + (size_t)gr * D_DIM + ((lane16 ^ (gr & 15)) << 4);
            __builtin_amdgcn_global_load_lds(
                (const __attribute__((address_space(1))) void*)src,
                (__attribute__((address_space(3))) void*)(&Bs[buf][0] + c * 1024),
                16, 0, 0);
        }
    };

    float allp[4][4] = {};
    float posp[4][4] = {};

    // prologue: stage tiles 0 and 1; drain tile 0 only (vmcnt(4) leaves tile 1)
    stage(0, 0);
    stage(1, 1);
    asm volatile("s_waitcnt vmcnt(4)" ::: "memory");
    __builtin_amdgcn_sched_barrier(0);
    __builtin_amdgcn_s_barrier();
    __builtin_amdgcn_sched_barrier(0);

    int cur = 0;
    for (int t = 0; t < NT; ++t) {
        // column labels early (hide under MFMA)
        const int jc    = jbase + t * BN + wc * 32 + lane16;
        const int labc0 = labels[jc];
        const int labc1 = labels[jc + 16];

        // ---- hoist all 8 b128 B-loads, then 64 MFMAs ----
        long bl[2][4], bh[2][4];
        #pragma unroll
        for (int n = 0; n < 2; ++n) {
            const int tr = wc * 32 + n * 16 + lane16;     // B row (output col)
            #pragma unroll
            for (int j = 0; j < 4; ++j) {
                int phys = (j * 4 + kgrp) ^ lane16;       // swizzled 16B slot
                long2 v = *reinterpret_cast<const long2*>(
                    &Bs[cur][0] + tr * 256 + (phys << 4));
                bl[n][j] = v.x;                           // ks = 2j
                bh[n][j] = v.y;                           // ks = 2j+1
            }
        }

        f32x4 acc[4][2] = {};
        __builtin_amdgcn_s_setprio(1);
        #pragma unroll
        for (int j = 0; j < 4; ++j) {
            #pragma unroll
            for (int m = 0; m < 4; ++m)
                #pragma unroll
                for (int n = 0; n < 2; ++n)
                    acc[m][n] = __builtin_amdgcn_mfma_f32_16x16x32_fp8_fp8(
                        af[m][2 * j], bl[n][j], acc[m][n], 0, 0, 0);
            #pragma unroll
            for (int m = 0; m < 4; ++m)
                #pragma unroll
                for (int n = 0; n < 2; ++n)
                    acc[m][n] = __builtin_amdgcn_mfma_f32_16x16x32_fp8_fp8(
                        af[m][2 * j + 1], bh[n][j], acc[m][n], 0, 0, 0);
        }
        __builtin_amdgcn_s_setprio(0);

        // stage 2 tiles ahead into the buffer freed at step t-1
        if (t + 2 < NT) stage((cur + 2) % 3, t + 2);

        if (t < NT - 1) {
            // counted drain: own stage(t+1) loads complete; stage(t+2) stays
            // in flight across the barrier (never vmcnt(0) in the loop).
            if (t + 2 < NT) asm volatile("s_waitcnt vmcnt(4)" ::: "memory");
            else            asm volatile("s_waitcnt vmcnt(0)" ::: "memory");
            __builtin_amdgcn_sched_barrier(0);
            __builtin_amdgcn_s_barrier();
            __builtin_amdgcn_sched_barrier(0);
        }

        // ---- epilogue: exp2 + mask, accumulate row sums (overlaps others'
        //      next-step ds_reads/staging) ----
        #pragma unroll
        for (int m = 0; m < 4; ++m) {
            #pragma unroll
            for (int r = 0; r < 4; ++r) {
                float e0 = fast_exp2(acc[m][0][r]);   // == exp(logit/T)
                float e1 = fast_exp2(acc[m][1][r]);
                allp[m][r] += e0 + e1;
                int lr = (labp[m] >> (r * 8)) & 0xFF;
                posp[m][r] += (lr == labc0 ? e0 : 0.0f) + (lr == labc1 ? e1 : 0.0f);
            }
        }

        cur = (cur + 1) % 3;
    }

    // ---- final: reduce across the 16 col-lanes, one atomic per row ----
    #pragma unroll
    for (int m = 0; m < 4; ++m) {
        #pragma unroll
        for (int r = 0; r < 4; ++r) {
            float a = allp[m][r], p = posp[m][r];
            #pragma unroll
            for (int off = 1; off < 16; off <<= 1) {
                a += __shfl_xor(a, off);
                p += __shfl_xor(p, off);
            }
            if (lane16 == 0) {
                int grow = i0 + wr * 64 + m * 16 + kgrp * 4 + r;
                atomicAdd(&all_sum[grow], a);
                atomicAdd(&pos_sum[grow], p);
            }
        }
    }
}

// ---------------- kernel 3: final loss reduction ----------------------------
__global__ void loss_kernel(const float* __restrict__ pos_sum,
                            const float* __restrict__ all_sum,
                            float* __restrict__ out) {
    float acc = 0.0f;
    for (int i = threadIdx.x; i < N_ROWS; i += 1024)
        acc += logf(pos_sum[i] / all_sum[i]);
    #pragma unroll
    for (int off = 32; off; off >>= 1) acc += __shfl_xor(acc, off);
    __shared__ float red[16];
    int wv = threadIdx.x >> 6, lane = threadIdx.x & 63;
    if (lane == 0) red[wv] = acc;
    __syncthreads();
    if (threadIdx.x < 64) {
        float s = (threadIdx.x < 16) ? red[threadIdx.x] : 0.0f;
        #pragma unroll
        for (int off = 8; off; off >>= 1) s += __shfl_xor(s, off);
        if (threadIdx.x == 0) out[0] = -s / (float)N_ROWS;
    }
}

// ---------------- launch -----------------------------------------------------
extern "C" void kernel_launch(void* const* d_in, const int* in_sizes, int n_in,
                              void* d_out, int out_size, void* d_ws, size_t ws_size,
                              hipStream_t stream) {
    const float* out0   = (const float*)d_in[0];
    const float* out1   = (const float*)d_in[1];
    const int*   labels = (const int*)d_in[2];
    float*       out    = (float*)d_out;

    unsigned char* a_f8 = (unsigned char*)d_ws;
    unsigned char* b_f8 = a_f8 + (size_t)N_ROWS * D_DIM;
    float* pos  = (float*)(b_f8 + (size_t)N_ROWS * D_DIM);
    float* alls = pos + N_ROWS;

    norm_cast_kernel<<<2 * N_ROWS / 4, 256, 0, stream>>>(out0, out1, a_f8, b_f8, pos);

    fused_flash_kernel<<<JSPLIT * (N_ROWS / BM), 256, 0, stream>>>(a_f8, b_f8, labels, pos, alls);

    loss_kernel<<<1, 1024, 0, stream>>>(pos, alls, out);
}

// Round 15
// 42.116 us; speedup vs baseline: 3.6100x; 1.2472x over previous
//
#include <hip/hip_runtime.h>
#include <hip/hip_bf16.h>
#include <math.h>

#define N_ROWS 8192
#define D_DIM  256
#define BM 128
#define BN 64
#define JSPLIT 8
#define JRANGE (N_ROWS / JSPLIT)     // 1024
#define NT (JRANGE / BN)             // 16 j-steps per block

typedef __attribute__((ext_vector_type(4))) float f32x4;
typedef __attribute__((ext_vector_type(4))) int   i32x4;
typedef __attribute__((ext_vector_type(8))) int   i32x8;

// total scale: exp(dot*2) == exp2(dot * 2*log2(e)); sqrt folded onto A and B
#define CAST_SCALE 1.6986388f        // sqrt(2 * log2(e))
#define SCALE_ONE 127                // E8M0 exponent bias -> multiplier 1.0

__device__ __forceinline__ float fast_exp2(float x) {
#if __has_builtin(__builtin_amdgcn_exp2f)
    return __builtin_amdgcn_exp2f(x);
#else
    return exp2f(x);
#endif
}

// ------- kernel 1: L2-normalize rows, scale, cast to fp8 e4m3 (+ zero accum) -
__global__ void norm_cast_kernel(const float* __restrict__ out0,
                                 const float* __restrict__ out1,
                                 unsigned char* __restrict__ a_f8,
                                 unsigned char* __restrict__ b_f8,
                                 float* __restrict__ zero_me,   // pos+all, 2*N floats
                                 float* __restrict__ out) {
    int gtid = blockIdx.x * blockDim.x + threadIdx.x;
    if (gtid < 2 * N_ROWS) zero_me[gtid] = 0.0f;
    if (gtid == 0) out[0] = 0.0f;     // loss kernel accumulates atomically

    int wave = gtid >> 6;
    int lane = threadIdx.x & 63;
    const float* src    = (wave < N_ROWS) ? out0 : out1;
    unsigned char* dst  = (wave < N_ROWS) ? a_f8 : b_f8;
    int row = (wave < N_ROWS) ? wave : wave - N_ROWS;

    float4 v = *reinterpret_cast<const float4*>(src + (size_t)row * D_DIM + lane * 4);
    float ss = v.x * v.x + v.y * v.y + v.z * v.z + v.w * v.w;
    #pragma unroll
    for (int off = 32; off; off >>= 1) ss += __shfl_xor(ss, off);
    float inv = CAST_SCALE / fmaxf(sqrtf(ss), 1e-12f);

    int packed = __builtin_amdgcn_cvt_pk_fp8_f32(v.x * inv, v.y * inv, 0, 0);
    packed     = __builtin_amdgcn_cvt_pk_fp8_f32(v.z * inv, v.w * inv, packed, 1);
    *reinterpret_cast<unsigned int*>(dst + (size_t)row * D_DIM + lane * 4) =
        (unsigned int)packed;
}

// ------- kernel 2: MX-fp8 K=128 fused GEMM + exp2 + masked row-sums ---------
// r14 schedule (triple-buffer, counted vmcnt(4), raw s_barrier) with the MFMA
// family switched to mfma_scale_f32_16x16x128_f8f6f4, unit scales (exact fp8
// math, 2.3x pipe rate, 16 instead of 64 MFMAs per step). Natural K layout:
// each lane owns 32 contiguous fp8 (row = lane16, kblock = kgrp*32 within each
// K=128 half). LDS slot-XOR swizzle: phys 16B slot p of row r holds global
// slot p^(r&15); reads use p = g^lane16 -> conflict-free.
__global__ __launch_bounds__(256, 2)
void fused_flash_kernel(const unsigned char* __restrict__ A,
                        const unsigned char* __restrict__ B,
                        const int* __restrict__ labels,
                        float* __restrict__ pos_sum,
                        float* __restrict__ all_sum) {
    __shared__ unsigned char Bs[3][BN * D_DIM];   // 3 x 16 KB

    const int tid    = threadIdx.x;
    const int lane   = tid & 63;
    const int wid    = tid >> 6;        // 0..3
    const int wr     = wid >> 1;        // 0..1  (64-row band)
    const int wc     = wid & 1;         // 0..1  (32-col half)
    const int lane16 = lane & 15;
    const int kgrp   = lane >> 4;       // 0..3

    const int jsplit = blockIdx.x & 7;
    const int rowt   = blockIdx.x >> 3;
    const int i0     = rowt * BM;
    const int jbase  = jsplit * JRANGE;

    // ---- A fragments -> registers (once), PINNED (64 VGPR fp8) ----
    // af[m][h]: row = i0+wr*64+m*16+lane16, k bytes [h*128 + kgrp*32, +32)
    i32x8 af[4][2];
    #pragma unroll
    for (int m = 0; m < 4; ++m) {
        const unsigned char* ap =
            A + (size_t)(i0 + wr * 64 + m * 16 + lane16) * D_DIM + kgrp * 32;
        #pragma unroll
        for (int h = 0; h < 2; ++h) {
            i32x4 lo = *reinterpret_cast<const i32x4*>(ap + h * 128);
            i32x4 hi = *reinterpret_cast<const i32x4*>(ap + h * 128 + 16);
            af[m][h] = __builtin_shufflevector(lo, hi, 0, 1, 2, 3, 4, 5, 6, 7);
        }
    }
    #pragma unroll
    for (int m = 0; m < 4; ++m)
        #pragma unroll
        for (int h = 0; h < 2; ++h)
            asm volatile("" : "+v"(af[m][h]));

    // row labels (0..99 fit in a byte), packed 4-per-int, pinned
    int labp[4];
    #pragma unroll
    for (int m = 0; m < 4; ++m) {
        int4 v = *reinterpret_cast<const int4*>(labels + i0 + wr * 64 + m * 16 + kgrp * 4);
        labp[m] = v.x | (v.y << 8) | (v.z << 16) | (v.w << 24);
        asm volatile("" : "+v"(labp[m]));
    }

    // ---- B staging: 16 chunks of 1KB (4 rows x 256B), 4 per wave ----
    // LDS[row][phys] = global[row][phys ^ (row&15)]  (16B slots, 16 per row)
    auto stage = [&](int buf, int t) {
        const int jrow0 = jbase + t * BN;
        #pragma unroll
        for (int cc = 0; cc < 4; ++cc) {
            int c  = wid * 4 + cc;                  // chunk 0..15 (wave-uniform)
            int gr = jrow0 + c * 4 + kgrp;          // global B row
            const unsigned char* src =
                B + (size_t)gr * D_DIM + ((lane16 ^ (gr & 15)) << 4);
            __builtin_amdgcn_global_load_lds(
                (const __attribute__((address_space(1))) void*)src,
                (__attribute__((address_space(3))) void*)(&Bs[buf][0] + c * 1024),
                16, 0, 0);
        }
    };

    float allp[4][4] = {};
    float posp[4][4] = {};

    // prologue: stage tiles 0 and 1; drain tile 0 only (vmcnt(4) leaves tile 1)
    stage(0, 0);
    stage(1, 1);
    asm volatile("s_waitcnt vmcnt(4)" ::: "memory");
    __builtin_amdgcn_sched_barrier(0);
    __builtin_amdgcn_s_barrier();
    __builtin_amdgcn_sched_barrier(0);

    int cur = 0;
    for (int t = 0; t < NT; ++t) {
        // column labels early (hide under MFMA)
        const int jc    = jbase + t * BN + wc * 32 + lane16;
        const int labc0 = labels[jc];
        const int labc1 = labels[jc + 16];

        // ---- hoist all 8 b128 B-loads (4 x i32x8 operands), then 16 MFMAs ----
        i32x8 bv[2][2];
        #pragma unroll
        for (int n = 0; n < 2; ++n) {
            const int tr = wc * 32 + n * 16 + lane16;     // B row (output col)
            #pragma unroll
            for (int h = 0; h < 2; ++h) {
                int g0 = h * 8 + kgrp * 2;                // logical 16B slot
                i32x4 lo = *reinterpret_cast<const i32x4*>(
                    &Bs[cur][0] + tr * 256 + ((g0 ^ lane16) << 4));
                i32x4 hi = *reinterpret_cast<const i32x4*>(
                    &Bs[cur][0] + tr * 256 + (((g0 + 1) ^ lane16) << 4));
                bv[n][h] = __builtin_shufflevector(lo, hi, 0, 1, 2, 3, 4, 5, 6, 7);
            }
        }

        f32x4 acc[4][2] = {};
        __builtin_amdgcn_s_setprio(1);
        #pragma unroll
        for (int h = 0; h < 2; ++h)
            #pragma unroll
            for (int m = 0; m < 4; ++m)
                #pragma unroll
                for (int n = 0; n < 2; ++n)
                    acc[m][n] = __builtin_amdgcn_mfma_scale_f32_16x16x128_f8f6f4(
                        af[m][h], bv[n][h], acc[m][n],
                        0, 0,                     // cbsz=fp8(e4m3), blgp=fp8
                        0, SCALE_ONE,             // A scale: opsel 0, x1.0
                        0, SCALE_ONE);            // B scale: opsel 0, x1.0
        __builtin_amdgcn_s_setprio(0);

        // stage 2 tiles ahead into the buffer freed at step t-1
        if (t + 2 < NT) stage((cur + 2) % 3, t + 2);

        if (t < NT - 1) {
            // counted drain: stage(t+1) complete; stage(t+2) stays in flight.
            if (t + 2 < NT) asm volatile("s_waitcnt vmcnt(4)" ::: "memory");
            else            asm volatile("s_waitcnt vmcnt(0)" ::: "memory");
            __builtin_amdgcn_sched_barrier(0);
            __builtin_amdgcn_s_barrier();
            __builtin_amdgcn_sched_barrier(0);
        }

        // ---- epilogue: exp2 + mask, accumulate row sums in registers ----
        #pragma unroll
        for (int m = 0; m < 4; ++m) {
            #pragma unroll
            for (int r = 0; r < 4; ++r) {
                float e0 = fast_exp2(acc[m][0][r]);   // == exp(logit/T)
                float e1 = fast_exp2(acc[m][1][r]);
                allp[m][r] += e0 + e1;
                int lr = (labp[m] >> (r * 8)) & 0xFF;
                posp[m][r] += (lr == labc0 ? e0 : 0.0f) + (lr == labc1 ? e1 : 0.0f);
            }
        }

        cur = (cur + 1) % 3;
    }

    // ---- final: reduce across the 16 col-lanes, one atomic per row ----
    #pragma unroll
    for (int m = 0; m < 4; ++m) {
        #pragma unroll
        for (int r = 0; r < 4; ++r) {
            float a = allp[m][r], p = posp[m][r];
            #pragma unroll
            for (int off = 1; off < 16; off <<= 1) {
                a += __shfl_xor(a, off);
                p += __shfl_xor(p, off);
            }
            if (lane16 == 0) {
                int grow = i0 + wr * 64 + m * 16 + kgrp * 4 + r;
                atomicAdd(&all_sum[grow], a);
                atomicAdd(&pos_sum[grow], p);
            }
        }
    }
}

// ------- kernel 3: parallel loss reduction (out pre-zeroed by norm_cast) ----
__global__ void loss_kernel(const float* __restrict__ pos_sum,
                            const float* __restrict__ all_sum,
                            float* __restrict__ out) {
    int gid = blockIdx.x * blockDim.x + threadIdx.x;
    float acc = 0.0f;
    for (int i = gid; i < N_ROWS; i += gridDim.x * blockDim.x)
        acc += logf(pos_sum[i] / all_sum[i]);
    #pragma unroll
    for (int off = 32; off; off >>= 1) acc += __shfl_xor(acc, off);
    __shared__ float red[8];
    int wv = threadIdx.x >> 6, lane = threadIdx.x & 63;
    if (lane == 0) red[wv] = acc;
    __syncthreads();
    if (threadIdx.x == 0) {
        float s = 0.0f;
        #pragma unroll
        for (int w = 0; w < 8; ++w) s += red[w];
        atomicAdd(out, -s / (float)N_ROWS);
    }
}

// ---------------- launch -----------------------------------------------------
extern "C" void kernel_launch(void* const* d_in, const int* in_sizes, int n_in,
                              void* d_out, int out_size, void* d_ws, size_t ws_size,
                              hipStream_t stream) {
    const float* out0   = (const float*)d_in[0];
    const float* out1   = (const float*)d_in[1];
    const int*   labels = (const int*)d_in[2];
    float*       out    = (float*)d_out;

    unsigned char* a_f8 = (unsigned char*)d_ws;
    unsigned char* b_f8 = a_f8 + (size_t)N_ROWS * D_DIM;
    float* pos  = (float*)(b_f8 + (size_t)N_ROWS * D_DIM);
    float* alls = pos + N_ROWS;

    norm_cast_kernel<<<2 * N_ROWS / 4, 256, 0, stream>>>(out0, out1, a_f8, b_f8, pos, out);

    fused_flash_kernel<<<JSPLIT * (N_ROWS / BM), 256, 0, stream>>>(a_f8, b_f8, labels, pos, alls);

    loss_kernel<<<16, 512, 0, stream>>>(pos, alls, out);
}